// Round 1
// baseline (200.723 us; speedup 1.0000x reference)
//
#include <hip/hip_runtime.h>
#include <math.h>

// Problem constants
#define BB   2
#define CIN  256
#define HH   48
#define WWW  48
#define OC3  768          // 3*OC channels out of the 1x1 conv
#define NG   4            // groups
#define GOC  64           // channels per group
#define C2   32           // half group channels
#define KH   7
#define KW   7
#define KK   49
#define PP   2304         // 48*48 positions
#define HALF_P 1152       // PP/2
#define HALF_S 1568       // KK*C2

// ---------------------------------------------------------------------------
// Kernel 1: 1x1 conv as GEMM.  Y2[b, p, o] = sum_c X[b, c, p] * W[o, c]
// Output stored position-major (B, P, 768) so attention reads are coalesced.
// Tiles: 64(o) x 64(p) x 16(c), 256 threads, 4x4 microtile.
// ---------------------------------------------------------------------------
__global__ __launch_bounds__(256) void conv1x1_kernel(
    const float* __restrict__ X,   // (B, 256, 2304)
    const float* __restrict__ Wm,  // (768, 256)
    float* __restrict__ Y2)        // (B, 2304, 768)
{
    __shared__ float As[16][64];   // As[kk][om]  (weight tile, transposed)
    __shared__ float Bs[16][64];   // Bs[kk][pn]  (input tile)

    const int tid = threadIdx.x;
    const int bn  = blockIdx.x;        // p tile index (36)
    const int bm  = blockIdx.y;        // o tile index (12)
    const int b   = blockIdx.z;        // batch
    const int om0 = bm * 64;
    const int pn0 = bn * 64;
    const int tx  = tid & 15;          // p microtile
    const int ty  = tid >> 4;          // o microtile

    const float* Xb = X + (size_t)b * CIN * PP;
    float acc[4][4] = {};

    for (int k0 = 0; k0 < CIN; k0 += 16) {
        {   // load W tile (64 o x 16 c), store transposed
            int row = tid >> 2;          // 0..63 (o)
            int col = (tid & 3) * 4;     // 0,4,8,12 (c)
            float4 w4 = *(const float4*)&Wm[(size_t)(om0 + row) * CIN + k0 + col];
            As[col + 0][row] = w4.x;
            As[col + 1][row] = w4.y;
            As[col + 2][row] = w4.z;
            As[col + 3][row] = w4.w;
        }
        {   // load X tile (16 c x 64 p)
            int row = tid >> 4;          // 0..15 (c)
            int col = (tid & 15) * 4;    // p
            float4 x4 = *(const float4*)&Xb[(size_t)(k0 + row) * PP + pn0 + col];
            *(float4*)&Bs[row][col] = x4;
        }
        __syncthreads();
        #pragma unroll
        for (int kk = 0; kk < 16; ++kk) {
            float4 a4 = *(const float4*)&As[kk][ty * 4];
            float4 b4 = *(const float4*)&Bs[kk][tx * 4];
            float av[4] = {a4.x, a4.y, a4.z, a4.w};
            float bv[4] = {b4.x, b4.y, b4.z, b4.w};
            #pragma unroll
            for (int i = 0; i < 4; ++i)
                #pragma unroll
                for (int j = 0; j < 4; ++j)
                    acc[i][j] += av[i] * bv[j];
        }
        __syncthreads();
    }

    // store position-major: Y2[(b*P + p)*768 + o], vectorized along o
    float* Yb = Y2 + (size_t)b * PP * OC3;
    #pragma unroll
    for (int j = 0; j < 4; ++j) {
        int p = pn0 + tx * 4 + j;
        float4 o4 = make_float4(acc[0][j], acc[1][j], acc[2][j], acc[3][j]);
        *(float4*)&Yb[(size_t)p * OC3 + om0 + ty * 4] = o4;
    }
}

// ---------------------------------------------------------------------------
// Kernel 2: attention. One wave per (b, g, p').
// Channels in Y2: [0,256)=q, [256,512)=k, [512,768)=v.
// Key scramble (derived from concat(axis=1)+row-major reshape):
//   t = p' >= 1152; q' = p' - t*1152; g2 = 2g + t
//   s = k'*64 + lane; h1 = s >= 1568; r = s - h1*1568
//   source pos p = 2q' + h1 (same spatial row since p even, W even)
//   k = r>>5 (kernel tap), c = r&31
//   g2 < 4 : chan = 256 + g2*64 + c,        + rpe_h[g2, i, c]
//   g2 >= 4: chan = 256 + (g2-4)*64 + 32+c, + rpe_w[g2-4, j, c]
//   OOB patch reads contribute 0 + rpe (pad before patches, rpe after).
// ---------------------------------------------------------------------------
__global__ __launch_bounds__(256) void attn_kernel(
    const float* __restrict__ Y2,     // (B, 2304, 768)
    const float* __restrict__ rpe_h,  // (4,1,7,1,32)
    const float* __restrict__ rpe_w,  // (4,1,1,7,32)
    float* __restrict__ out)          // (B, 256, 48, 48)
{
    const int tid  = threadIdx.x;
    const int lane = tid & 63;
    const int wid  = blockIdx.x * 4 + (tid >> 6);   // 0 .. 18431
    const int pq   = wid % PP;                      // p'
    const int g    = (wid / PP) & (NG - 1);
    const int b    = wid / (PP * NG);
    const int ph   = pq / WWW;
    const int pw   = pq % WWW;

    const float* Yb = Y2 + (size_t)b * PP * OC3;

    // query: center tap, coalesced 64 channels
    const float q = Yb[(size_t)pq * OC3 + g * GOC + lane];

    // scramble params (wave-uniform)
    const int t   = (pq >= HALF_P) ? 1 : 0;
    const int qpr = pq - t * HALF_P;
    const int p0  = 2 * qpr;
    const int ph0 = p0 / WWW;
    const int pw0 = p0 % WWW;            // p0 even => p0+1 is same row
    const int g2  = 2 * g + t;
    const bool use_h = (g2 < NG);
    const int  kch   = use_h ? (CIN + g2 * GOC) : (CIN + (g2 - NG) * GOC + C2);
    const float* rpe = use_h ? (rpe_h + g2 * KH * C2) : (rpe_w + (g2 - NG) * KW * C2);

    // ---- logits: 49 chunks, each a 64-lane dot + butterfly reduce ----
    float logit = -INFINITY;
    for (int kp = 0; kp < KK; ++kp) {
        int s  = kp * 64 + lane;
        int h1 = (s >= HALF_S) ? 1 : 0;
        int r  = s - h1 * HALF_S;
        int k  = r >> 5;
        int c  = r & 31;
        int i  = (k * 37) >> 8;          // k / 7 for k < 49
        int j  = k - i * 7;
        int yh = ph0 + i - 3;
        int yw = pw0 + h1 + j - 3;
        float kv = 0.f;
        if ((unsigned)yh < 48u && (unsigned)yw < 48u)
            kv = Yb[(size_t)(yh * WWW + yw) * OC3 + kch + c];
        int ij = use_h ? i : j;
        kv += rpe[ij * C2 + c];
        float prod = q * kv;
        #pragma unroll
        for (int m = 1; m < 64; m <<= 1)
            prod += __shfl_xor(prod, m, 64);
        if (lane == kp) logit = prod;
    }

    // ---- softmax over lanes 0..48 ----
    float mx = logit;
    #pragma unroll
    for (int d = 1; d < 64; d <<= 1)
        mx = fmaxf(mx, __shfl_xor(mx, d, 64));
    float e = (lane < KK) ? __expf(logit - mx) : 0.f;
    float ssum = e;
    #pragma unroll
    for (int d = 1; d < 64; d <<= 1)
        ssum += __shfl_xor(ssum, d, 64);
    const float att = e / ssum;

    // ---- value accumulation: lane = output channel cc ----
    float acc = 0.f;
    const int vch = 2 * CIN + g * GOC + lane;
    #pragma unroll
    for (int k = 0; k < KK; ++k) {
        float ak = __shfl(att, k, 64);
        int i = k / 7, j = k % 7;        // compile-time (unrolled)
        int yh = ph + i - 3;
        int yw = pw + j - 3;
        if ((unsigned)yh < 48u && (unsigned)yw < 48u)
            acc += ak * Yb[(size_t)(yh * WWW + yw) * OC3 + vch];
    }

    // out[b, g*64+lane, ph, pw]
    out[(((size_t)b * 256 + g * GOC + lane) * 48 + ph) * 48 + pw] = acc;
}

// ---------------------------------------------------------------------------
extern "C" void kernel_launch(void* const* d_in, const int* in_sizes, int n_in,
                              void* d_out, int out_size, void* d_ws, size_t ws_size,
                              hipStream_t stream)
{
    const float* x  = (const float*)d_in[0];   // (2,256,48,48)
    const float* w  = (const float*)d_in[1];   // (768,256)
    const float* rh = (const float*)d_in[2];   // (4,1,7,1,32)
    const float* rw = (const float*)d_in[3];   // (4,1,1,7,32)
    float* Y2 = (float*)d_ws;                  // needs B*2304*768*4 = 14.2 MB

    dim3 gridC(PP / 64, OC3 / 64, BB);         // 36 x 12 x 2
    conv1x1_kernel<<<gridC, 256, 0, stream>>>(x, w, Y2);

    const int nwaves = BB * NG * PP;           // 18432
    attn_kernel<<<nwaves / 4, 256, 0, stream>>>(Y2, rh, rw, (float*)d_out);
}